// Round 1
// baseline (123.459 us; speedup 1.0000x reference)
//
#include <hip/hip_runtime.h>
#include <hip/hip_bf16.h>

#define SEQ 8192
#define HD 128
#define BM 128
#define BN 64
#define NQT (SEQ / BM)   // 64
#define THREADS 512

typedef __bf16 bf16_t;
typedef __bf16 bf16x2 __attribute__((ext_vector_type(2)));
typedef __bf16 bf16x8 __attribute__((ext_vector_type(8)));
typedef float f32x4 __attribute__((ext_vector_type(4)));
typedef float f32x16 __attribute__((ext_vector_type(16)));
typedef unsigned int u32x4 __attribute__((ext_vector_type(4)));

#if __has_builtin(__builtin_amdgcn_exp2f)
__device__ inline float exp2_fast(float x) { return __builtin_amdgcn_exp2f(x); }
#else
__device__ inline float exp2_fast(float x) { return exp2f(x); }
#endif

// async global->LDS DMA, 16 B per lane; lds dest wave-uniform, HW adds lane*16
__device__ inline void load_lds16(const void* g, void* l) {
  __builtin_amdgcn_global_load_lds(
      (const __attribute__((address_space(1))) void*)g,
      (__attribute__((address_space(3))) void*)l, 16, 0, 0);
}

// ---------------- prep ----------------
// Kb blocked: [tile T][d-chunk c 0..15][key r 0..63][8]  = K[T*64+r][c*8+j]
// VT blocked: [tile T][key-chunk kc 0..7][d 0..127][8]   = V[T*64+kc*8+j][d]
__global__ __launch_bounds__(256) void prep_kernel(const float* __restrict__ K,
                                                   const float* __restrict__ V,
                                                   bf16_t* __restrict__ Kb,
                                                   bf16_t* __restrict__ VT) {
  const int b = (int)blockIdx.x;
  const int tid = (int)threadIdx.x;
  if (b < 256) {
    // V tile: 64 keys x 64 d, staged f32 in LDS (coalesced reads)
    __shared__ float tile[64][65];
    const int T = b & 127;
    const int d0 = (b >> 7) * 64;
    const int s0 = T * 64;
    const int r = tid >> 2;          // 0..63 (key)
    const int c0 = (tid & 3) * 16;   // d offset
#pragma unroll
    for (int j4 = 0; j4 < 4; ++j4) {
      float4 x = *(const float4*)&V[(size_t)(s0 + r) * HD + d0 + c0 + j4 * 4];
      tile[r][c0 + j4 * 4 + 0] = x.x;
      tile[r][c0 + j4 * 4 + 1] = x.y;
      tile[r][c0 + j4 * 4 + 2] = x.z;
      tile[r][c0 + j4 * 4 + 3] = x.w;
    }
    __syncthreads();
    const int d_l = tid & 63;
    const int kc0 = (tid >> 6) * 2;  // 0,2,4,6
#pragma unroll
    for (int k2 = 0; k2 < 2; ++k2) {
      const int kc = kc0 + k2;
      bf16x8 wv;
#pragma unroll
      for (int j = 0; j < 8; ++j) wv[j] = (bf16_t)tile[kc * 8 + j][d_l];
      *(bf16x8*)&VT[((size_t)(T * 8 + kc) * 128 + d0 + d_l) * 8] = wv;
    }
  } else {
    // K convert: one 16B chunk per thread
    const int base = (b - 256) * 2048 + tid * 8;   // flat over 8192*128
    const int row = base >> 7;
    const int c = (base >> 3) & 15;
    const int T = row >> 6;
    const int r = row & 63;
    float4 a = *(const float4*)&K[base];
    float4 cc = *(const float4*)&K[base + 4];
    bf16x8 f;
    f[0] = (bf16_t)a.x; f[1] = (bf16_t)a.y; f[2] = (bf16_t)a.z; f[3] = (bf16_t)a.w;
    f[4] = (bf16_t)cc.x; f[5] = (bf16_t)cc.y; f[6] = (bf16_t)cc.z; f[7] = (bf16_t)cc.w;
    *(bf16x8*)&Kb[((size_t)(T * 16 + c) * 64 + r) * 8] = f;
  }
}

// ---------------- main flash-attention kernel ----------------
// 8 waves: qw = w&3 (32 q-rows), g = w>>2 (key-half). Wave (qw,g): QK^T for
// its 32 keys (S^T layout), exp, half-wave exchange -> P stays IN REGISTERS
// as the PV A-fragment; PV accumulates O(32q x 128d) over own keys only.
// Epilogue sums the g=0/g=1 partial O's once via LDS (reusing the K/V arena).
// One barrier per iteration (buffer swap + DMA drain); DMA issued at iter
// start has the whole iteration's compute to land.
__global__ __launch_bounds__(THREADS, 4) void fattn_kernel(
    const float* __restrict__ Q, const bf16_t* __restrict__ Kb,
    const bf16_t* __restrict__ VT, float* __restrict__ Opart,
    float* __restrict__ Lpart, int kshift, int nit) {
  // arena: [0,32K) = kt double buffer, [32K,64K) = vt double buffer.
  // kt layout per buf: [d-chunk 0..15][key 0..63][8] bf16  (1 KB per chunk row)
  // vt layout per buf: [key-chunk8 0..7][d 0..127][8] bf16
  // epilogue reuses whole arena as float[4][32][128] (O partial exchange)
  __shared__ __align__(16) char smem[65536];
  __shared__ float lbuf[128];

  const int tid = (int)threadIdx.x;
  const int lane = tid & 63;
  const int w = tid >> 6;
  const int qw = w & 3;
  const int g = w >> 2;
  const int h = lane >> 5;
  const int n32 = lane & 31;

  const int qt = (int)blockIdx.x >> kshift;
  const int sp = (int)blockIdx.x & ((1 << kshift) - 1);
  const int qbase = qt * BM;
  const int tile0 = sp * nit;          // first 64-key tile index

  const float SC2 = 0.08838834764831845f * 1.4426950408889634f; // (1/sqrt(128))*log2e

  // Q B-frags (n = n32 = q-row, k-dim = d), pre-scaled
  bf16x8 qf[8];
  {
    const float* qp = Q + (size_t)(qbase + qw * 32 + n32) * HD + h * 8;
#pragma unroll
    for (int kk = 0; kk < 8; ++kk) {
      float4 a = *(const float4*)(qp + kk * 16);
      float4 b = *(const float4*)(qp + kk * 16 + 4);
      bf16x8 f;
      f[0] = (bf16_t)(a.x * SC2); f[1] = (bf16_t)(a.y * SC2);
      f[2] = (bf16_t)(a.z * SC2); f[3] = (bf16_t)(a.w * SC2);
      f[4] = (bf16_t)(b.x * SC2); f[5] = (bf16_t)(b.y * SC2);
      f[6] = (bf16_t)(b.z * SC2); f[7] = (bf16_t)(b.w * SC2);
      qf[kk] = f;
    }
  }

  f32x16 o_acc[4];   // O[32q x 128d] partial (own 32 keys)
#pragma unroll
  for (int i = 0; i < 4; ++i)
#pragma unroll
    for (int e = 0; e < 16; ++e) o_acc[i][e] = 0.f;
  float l_acc = 0.f;

  const int rr0 = w * 2;   // DMA region indices rr0, rr0+1
  const int klane = h * 1024 + (g * 32 + n32) * 16;          // kt byte offset
  const int vlane = g * 8192 + h * 2048 + n32 * 16;          // vt byte offset

  // ---- preload tile0 into buffer 0 ----
#pragma unroll
  for (int t = 0; t < 2; ++t) {
    const int rr = rr0 + t;
    load_lds16(Kb + ((size_t)(tile0 * 16 + rr) * 64 + lane) * 8,
               smem + rr * 1024);
    load_lds16(VT + ((size_t)(tile0 * 8 + (rr >> 1)) * 128 + (rr & 1) * 64 + lane) * 8,
               smem + 32768 + rr * 1024);
  }
  __syncthreads();

  for (int it = 0; it < nit; ++it) {
    const int cur = it & 1;
    const int nxt = cur ^ 1;
    // issue next-tile DMA (in flight across the whole iteration)
    if (it + 1 < nit) {
      const int ntile = tile0 + it + 1;
#pragma unroll
      for (int t = 0; t < 2; ++t) {
        const int rr = rr0 + t;
        load_lds16(Kb + ((size_t)(ntile * 16 + rr) * 64 + lane) * 8,
                   smem + nxt * 16384 + rr * 1024);
        load_lds16(VT + ((size_t)(ntile * 8 + (rr >> 1)) * 128 + (rr & 1) * 64 + lane) * 8,
                   smem + 32768 + nxt * 16384 + rr * 1024);
      }
    }

    // ---- S^T(key-half g) = K_g Q^T : 32 x 32, K-dim 128 ----
    const char* kb = smem + cur * 16384 + klane;
    f32x16 sacc;
#pragma unroll
    for (int e = 0; e < 16; ++e) sacc[e] = 0.f;
#pragma unroll
    for (int kk = 0; kk < 8; ++kk) {
      bf16x8 af = *(const bf16x8*)(kb + kk * 2048);
      sacc = __builtin_amdgcn_mfma_f32_32x32x16_bf16(af, qf[kk], sacc, 0, 0, 0);
    }

    // ---- exp -> pack -> half-wave exchange -> P A-frags in registers ----
    // sacc[r] = S^T[key = g*32 + (r&3)+8*(r>>2)+4h][q = n32]
    bf16x8 pa[2];
#pragma unroll
    for (int kk2 = 0; kk2 < 2; ++kk2) {
      float pf[8];
#pragma unroll
      for (int j = 0; j < 8; ++j) pf[j] = exp2_fast(sacc[8 * kk2 + j]);
      l_acc += ((pf[0] + pf[1]) + (pf[2] + pf[3])) +
               ((pf[4] + pf[5]) + (pf[6] + pf[7]));
      bf16x2 p0, p1, p2, p3;
      p0[0] = (bf16_t)pf[0]; p0[1] = (bf16_t)pf[1];
      p1[0] = (bf16_t)pf[2]; p1[1] = (bf16_t)pf[3];
      p2[0] = (bf16_t)pf[4]; p2[1] = (bf16_t)pf[5];
      p3[0] = (bf16_t)pf[6]; p3[1] = (bf16_t)pf[7];
      const unsigned int sA = __builtin_bit_cast(unsigned int, p0);
      const unsigned int sB = __builtin_bit_cast(unsigned int, p1);
      const unsigned int sC = __builtin_bit_cast(unsigned int, p2);
      const unsigned int sD = __builtin_bit_cast(unsigned int, p3);
      unsigned int s0 = h ? sA : sC, s1 = h ? sB : sD;
      unsigned int r0 = __shfl_xor(s0, 32);
      unsigned int r1 = __shfl_xor(s1, 32);
      unsigned int o0 = h ? sC : sA, o1 = h ? sD : sB;
      u32x4 fv;
      fv[0] = h ? r0 : o0; fv[1] = h ? r1 : o1;
      fv[2] = h ? o0 : r0; fv[3] = h ? o1 : r1;
      // fv = P[q=n32][key16-chunk g*2+kk2][8h + j]  == A-frag directly
      pa[kk2] = __builtin_bit_cast(bf16x8, fv);
    }

    // ---- O(all 128 d) += P(own 32 keys) V ----
    const char* vb0 = smem + 32768 + cur * 16384 + vlane;
#pragma unroll
    for (int kc = 0; kc < 2; ++kc) {
#pragma unroll
      for (int ot = 0; ot < 4; ++ot) {
        bf16x8 vb = *(const bf16x8*)(vb0 + kc * 4096 + ot * 512);
        o_acc[ot] = __builtin_amdgcn_mfma_f32_32x32x16_bf16(pa[kc], vb, o_acc[ot], 0, 0, 0);
      }
    }

    __syncthreads();   // drains DMA (vmcnt) + kt/vt reads; buffer swap
  }

  // ---- epilogue: sum g=0/g=1 partial O via LDS, store; l combine ----
  float* obuf = (float*)smem;   // [4 qw][32 row][128 d]
  if (g == 1) {
#pragma unroll
    for (int ot = 0; ot < 4; ++ot)
#pragma unroll
      for (int reg = 0; reg < 16; ++reg) {
        const int row = (reg & 3) + 8 * (reg >> 2) + 4 * h;
        obuf[(qw * 32 + row) * 128 + ot * 32 + n32] = o_acc[ot][reg];
      }
    float l = l_acc + __shfl_xor(l_acc, 32);   // own 32 keys, per q
    if (lane < 32) lbuf[qw * 32 + n32] = l;
  }
  __syncthreads();
  if (g == 0) {
    float* op = Opart + ((size_t)sp * SEQ + qbase + qw * 32) * HD;
#pragma unroll
    for (int ot = 0; ot < 4; ++ot)
#pragma unroll
      for (int reg = 0; reg < 16; ++reg) {
        const int row = (reg & 3) + 8 * (reg >> 2) + 4 * h;
        op[row * HD + ot * 32 + n32] =
            o_acc[ot][reg] + obuf[(qw * 32 + row) * 128 + ot * 32 + n32];
      }
    float l = l_acc + __shfl_xor(l_acc, 32);
    if (lane < 32)
      Lpart[(size_t)sp * SEQ + qbase + qw * 32 + n32] = l + lbuf[qw * 32 + n32];
  }
}

// ---------------- combine: out = sum_s O_s / sum_s l_s ----------------
__global__ __launch_bounds__(256) void combine_kernel(const float* __restrict__ Opart,
                                                      const float* __restrict__ Lpart,
                                                      float* __restrict__ out, int ksplit) {
  const int tid = (int)threadIdx.x;
  const int row = (int)blockIdx.x * 8 + (tid >> 5);
  const int c0 = (tid & 31) * 4;
  float lsum = 0.f;
  for (int s = 0; s < ksplit; ++s) lsum += Lpart[(size_t)s * SEQ + row];
  f32x4 acc;
#pragma unroll
  for (int e = 0; e < 4; ++e) acc[e] = 0.f;
  for (int s = 0; s < ksplit; ++s) {
    f32x4 o = *(const f32x4*)&Opart[((size_t)s * SEQ + row) * HD + c0];
#pragma unroll
    for (int e = 0; e < 4; ++e) acc[e] += o[e];
  }
  const float inv = 1.0f / lsum;
  f32x4 res;
#pragma unroll
  for (int e = 0; e < 4; ++e) res[e] = acc[e] * inv;
  *(f32x4*)&out[(size_t)row * HD + c0] = res;
}

extern "C" void kernel_launch(void* const* d_in, const int* in_sizes, int n_in,
                              void* d_out, int out_size, void* d_ws, size_t ws_size,
                              hipStream_t stream) {
  const float* Q = (const float*)d_in[0];
  const float* K = (const float*)d_in[1];
  const float* V = (const float*)d_in[2];
  float* out = (float*)d_out;

  int ksplit = 8, kshift = 3;
  while (ksplit > 1) {
    size_t need = (size_t)ksplit * SEQ * HD * 4
                + (size_t)ksplit * SEQ * 4
                + (size_t)SEQ * HD * 2 * 2;
    if (need <= ws_size) break;
    ksplit >>= 1; kshift--;
  }

  char* ws = (char*)d_ws;
  float* Opart = (float*)ws;
  float* Lpart = (float*)(ws + (size_t)ksplit * SEQ * HD * 4);
  bf16_t* Kb = (bf16_t*)(ws + (size_t)ksplit * SEQ * HD * 4 + (size_t)ksplit * SEQ * 4);
  bf16_t* VT = Kb + (size_t)SEQ * HD;

  const int nit = SEQ / (ksplit * BN);

  prep_kernel<<<768, 256, 0, stream>>>(K, V, Kb, VT);
  fattn_kernel<<<NQT * ksplit, THREADS, 0, stream>>>(Q, Kb, VT, Opart, Lpart, kshift, nit);
  combine_kernel<<<SEQ / 8, 256, 0, stream>>>(Opart, Lpart, out, ksplit);
}

// Round 2
// 118.532 us; speedup vs baseline: 1.0416x; 1.0416x over previous
//
#include <hip/hip_runtime.h>
#include <hip/hip_bf16.h>

#define SEQ 8192
#define HD 128
#define BM 128
#define BN 64
#define NQT (SEQ / BM)   // 64
#define THREADS 512

typedef __bf16 bf16_t;
typedef __bf16 bf16x2 __attribute__((ext_vector_type(2)));
typedef __bf16 bf16x8 __attribute__((ext_vector_type(8)));
typedef float f32x4 __attribute__((ext_vector_type(4)));
typedef float f32x16 __attribute__((ext_vector_type(16)));
typedef unsigned int u32x4 __attribute__((ext_vector_type(4)));

#if __has_builtin(__builtin_amdgcn_exp2f)
__device__ inline float exp2_fast(float x) { return __builtin_amdgcn_exp2f(x); }
#else
__device__ inline float exp2_fast(float x) { return exp2f(x); }
#endif

// async global->LDS DMA, 16 B per lane; lds dest wave-uniform, HW adds lane*16
__device__ inline void load_lds16(const void* g, void* l) {
  __builtin_amdgcn_global_load_lds(
      (const __attribute__((address_space(1))) void*)g,
      (__attribute__((address_space(3))) void*)l, 16, 0, 0);
}

// ---------------- prep ----------------
// Kb blocked: [tile T][d-chunk c 0..15][key r 0..63][8]  = K[T*64+r][c*8+j]
// VT blocked: [tile T][key-chunk kc 0..7][d 0..127][8]   = V[T*64+kc*8+j][d]
__global__ __launch_bounds__(256) void prep_kernel(const float* __restrict__ K,
                                                   const float* __restrict__ V,
                                                   bf16_t* __restrict__ Kb,
                                                   bf16_t* __restrict__ VT) {
  const int b = (int)blockIdx.x;
  const int tid = (int)threadIdx.x;
  if (b < 256) {
    // V tile: 64 keys x 64 d, staged f32 in LDS (coalesced reads)
    __shared__ float tile[64][65];
    const int T = b & 127;
    const int d0 = (b >> 7) * 64;
    const int s0 = T * 64;
    const int r = tid >> 2;          // 0..63 (key)
    const int c0 = (tid & 3) * 16;   // d offset
#pragma unroll
    for (int j4 = 0; j4 < 4; ++j4) {
      float4 x = *(const float4*)&V[(size_t)(s0 + r) * HD + d0 + c0 + j4 * 4];
      tile[r][c0 + j4 * 4 + 0] = x.x;
      tile[r][c0 + j4 * 4 + 1] = x.y;
      tile[r][c0 + j4 * 4 + 2] = x.z;
      tile[r][c0 + j4 * 4 + 3] = x.w;
    }
    __syncthreads();
    const int d_l = tid & 63;
    const int kc0 = (tid >> 6) * 2;  // 0,2,4,6
#pragma unroll
    for (int k2 = 0; k2 < 2; ++k2) {
      const int kc = kc0 + k2;
      bf16x8 wv;
#pragma unroll
      for (int j = 0; j < 8; ++j) wv[j] = (bf16_t)tile[kc * 8 + j][d_l];
      *(bf16x8*)&VT[((size_t)(T * 8 + kc) * 128 + d0 + d_l) * 8] = wv;
    }
  } else {
    // K convert: one 16B chunk per thread
    const int base = (b - 256) * 2048 + tid * 8;   // flat over 8192*128
    const int row = base >> 7;
    const int c = (base >> 3) & 15;
    const int T = row >> 6;
    const int r = row & 63;
    float4 a = *(const float4*)&K[base];
    float4 cc = *(const float4*)&K[base + 4];
    bf16x8 f;
    f[0] = (bf16_t)a.x; f[1] = (bf16_t)a.y; f[2] = (bf16_t)a.z; f[3] = (bf16_t)a.w;
    f[4] = (bf16_t)cc.x; f[5] = (bf16_t)cc.y; f[6] = (bf16_t)cc.z; f[7] = (bf16_t)cc.w;
    *(bf16x8*)&Kb[((size_t)(T * 16 + c) * 64 + r) * 8] = f;
  }
}

// ---------------- main flash-attention kernel ----------------
// 8 waves: qw = w&3 (32 q-rows), g = w>>2. Wave (qw,g): QK^T for key-half g
// (S^T layout), exp, write A-layout P chunks to LDS; after an lgkm-only
// barrier (no vmcnt drain -- keeps the next-tile DMA in flight across the
// whole iteration), PV over ALL 64 keys restricted to d-half g.
// End-of-iteration __syncthreads() does the vmcnt(0) drain for the buffer
// swap, by which point the DMA has had the full iteration to land.
__global__ __launch_bounds__(THREADS, 4) void fattn_kernel(
    const float* __restrict__ Q, const bf16_t* __restrict__ Kb,
    const bf16_t* __restrict__ VT, float* __restrict__ Opart,
    float* __restrict__ Lpart, int kshift, int nit) {
  __shared__ __align__(16) bf16_t kt2[2][16][64][8];  // 32 KB [buf][d-chunk][key][8]
  __shared__ __align__(16) bf16_t vt2[2][8][128][8];  // 32 KB [buf][key-chunk][d][8]
  __shared__ __align__(16) char pbuf[4][4][64][16];   // 16 KB [qw][key-chunk16][lane][16B]

  const int tid = (int)threadIdx.x;
  const int lane = tid & 63;
  const int w = tid >> 6;
  const int qw = w & 3;
  const int g = w >> 2;
  const int h = lane >> 5;
  const int n32 = lane & 31;

  const int qt = (int)blockIdx.x >> kshift;
  const int sp = (int)blockIdx.x & ((1 << kshift) - 1);
  const int qbase = qt * BM;
  const int tile0 = sp * nit;          // first 64-key tile index

  const float SC2 = 0.08838834764831845f * 1.4426950408889634f; // (1/sqrt(128))*log2e

  // Q B-frags (n = n32 = q-row, k-dim = d), pre-scaled
  bf16x8 qf[8];
  {
    const float* qp = Q + (size_t)(qbase + qw * 32 + n32) * HD + h * 8;
#pragma unroll
    for (int kk = 0; kk < 8; ++kk) {
      float4 a = *(const float4*)(qp + kk * 16);
      float4 b = *(const float4*)(qp + kk * 16 + 4);
      bf16x8 f;
      f[0] = (bf16_t)(a.x * SC2); f[1] = (bf16_t)(a.y * SC2);
      f[2] = (bf16_t)(a.z * SC2); f[3] = (bf16_t)(a.w * SC2);
      f[4] = (bf16_t)(b.x * SC2); f[5] = (bf16_t)(b.y * SC2);
      f[6] = (bf16_t)(b.z * SC2); f[7] = (bf16_t)(b.w * SC2);
      qf[kk] = f;
    }
  }

  f32x16 o_acc[2];
#pragma unroll
  for (int i = 0; i < 2; ++i)
#pragma unroll
    for (int e = 0; e < 16; ++e) o_acc[i][e] = 0.f;
  float l_acc = 0.f;

  const int rr0 = w * 2;   // DMA region indices rr0, rr0+1

  // ---- preload tile0 into buffer 0 ----
#pragma unroll
  for (int t = 0; t < 2; ++t) {
    const int rr = rr0 + t;
    load_lds16(Kb + ((size_t)(tile0 * 16 + rr) * 64 + lane) * 8,
               (char*)&kt2[0][0][0][0] + rr * 1024);
    load_lds16(VT + ((size_t)(tile0 * 8 + (rr >> 1)) * 128 + (rr & 1) * 64 + lane) * 8,
               (char*)&vt2[0][0][0][0] + rr * 1024);
  }
  __syncthreads();

  for (int it = 0; it < nit; ++it) {
    const int cur = it & 1;
    const int nxt = cur ^ 1;
    const int ntile = tile0 + ((it + 1 < nit) ? it + 1 : 0);
    // issue next-tile DMA (in flight across the whole iteration)
#pragma unroll
    for (int t = 0; t < 2; ++t) {
      const int rr = rr0 + t;
      load_lds16(Kb + ((size_t)(ntile * 16 + rr) * 64 + lane) * 8,
                 (char*)&kt2[nxt][0][0][0] + rr * 1024);
      load_lds16(VT + ((size_t)(ntile * 8 + (rr >> 1)) * 128 + (rr & 1) * 64 + lane) * 8,
                 (char*)&vt2[nxt][0][0][0] + rr * 1024);
    }

    // ---- S^T(key-half g) = K_g Q^T : 32 x 32, K-dim 128 ----
    f32x16 sacc;
#pragma unroll
    for (int e = 0; e < 16; ++e) sacc[e] = 0.f;
#pragma unroll
    for (int kk = 0; kk < 8; ++kk) {
      bf16x8 af = *(const bf16x8*)&kt2[cur][2 * kk + h][g * 32 + n32][0];
      sacc = __builtin_amdgcn_mfma_f32_32x32x16_bf16(af, qf[kk], sacc, 0, 0, 0);
    }

    // ---- exp -> pack -> half-wave exchange -> write A-layout P chunks ----
    // sacc[r] = S^T[key = g*32 + (r&3)+8*(r>>2)+4h][q = n32]
#pragma unroll
    for (int kk2 = 0; kk2 < 2; ++kk2) {
      float pf[8];
#pragma unroll
      for (int j = 0; j < 8; ++j) pf[j] = exp2_fast(sacc[8 * kk2 + j]);
#pragma unroll
      for (int j = 0; j < 8; ++j) l_acc += pf[j];
      bf16x2 p0, p1, p2, p3;
      p0[0] = (bf16_t)pf[0]; p0[1] = (bf16_t)pf[1];
      p1[0] = (bf16_t)pf[2]; p1[1] = (bf16_t)pf[3];
      p2[0] = (bf16_t)pf[4]; p2[1] = (bf16_t)pf[5];
      p3[0] = (bf16_t)pf[6]; p3[1] = (bf16_t)pf[7];
      const unsigned int sA = __builtin_bit_cast(unsigned int, p0);
      const unsigned int sB = __builtin_bit_cast(unsigned int, p1);
      const unsigned int sC = __builtin_bit_cast(unsigned int, p2);
      const unsigned int sD = __builtin_bit_cast(unsigned int, p3);
      unsigned int s0 = h ? sA : sC, s1 = h ? sB : sD;
      unsigned int r0 = __shfl_xor(s0, 32);
      unsigned int r1 = __shfl_xor(s1, 32);
      unsigned int o0 = h ? sC : sA, o1 = h ? sD : sB;
      u32x4 fv;
      fv[0] = h ? r0 : o0; fv[1] = h ? r1 : o1;
      fv[2] = h ? o0 : r0; fv[3] = h ? o1 : r1;
      *(u32x4*)&pbuf[qw][g * 2 + kk2][lane][0] = fv;   // lane-linear write
    }

    // P visible to sibling wave: lgkm-only barrier (ds_write tracked by
    // lgkmcnt; the in-flight global_load_lds DMA is vmcnt and stays live).
    asm volatile("s_waitcnt lgkmcnt(0)\n\ts_barrier" ::: "memory");
    __builtin_amdgcn_sched_barrier(0);

    // ---- O(d-half g) += P(all 64 keys) V ----
#pragma unroll
    for (int C = 0; C < 4; ++C) {
      bf16x8 pa = *(const bf16x8*)&pbuf[qw][C][h * 32 + n32][0];
#pragma unroll
      for (int ot = 0; ot < 2; ++ot) {
        bf16x8 vb = *(const bf16x8*)&vt2[cur][C * 2 + h][g * 64 + ot * 32 + n32][0];
        o_acc[ot] = __builtin_amdgcn_mfma_f32_32x32x16_bf16(pa, vb, o_acc[ot], 0, 0, 0);
      }
    }

    __syncthreads();   // drains DMA (vmcnt) + pbuf/vt reads; buffer swap
  }

  // ---- epilogue: O block store (distinct q x d block per wave) + l combine ----
  {
    float* op = Opart + ((size_t)sp * SEQ + qbase + qw * 32) * HD + g * 64;
#pragma unroll
    for (int ot = 0; ot < 2; ++ot)
#pragma unroll
      for (int reg = 0; reg < 16; ++reg) {
        const int row = (reg & 3) + 8 * (reg >> 2) + 4 * h;
        op[row * HD + ot * 32 + n32] = o_acc[ot][reg];
      }
    float l = l_acc + __shfl_xor(l_acc, 32);   // this wave's 32 keys, per q
    float* lfb = (float*)pbuf;
    if (lane < 32) lfb[g * 128 + qw * 32 + n32] = l;
    __syncthreads();
    if (g == 0 && lane < 32)
      Lpart[(size_t)sp * SEQ + qbase + qw * 32 + n32] =
          l + lfb[128 + qw * 32 + n32];
  }
}

// ---------------- combine: out = sum_s O_s / sum_s l_s ----------------
__global__ __launch_bounds__(256) void combine_kernel(const float* __restrict__ Opart,
                                                      const float* __restrict__ Lpart,
                                                      float* __restrict__ out, int ksplit) {
  const int tid = (int)threadIdx.x;
  const int row = (int)blockIdx.x * 8 + (tid >> 5);
  const int c0 = (tid & 31) * 4;
  float lsum = 0.f;
  for (int s = 0; s < ksplit; ++s) lsum += Lpart[(size_t)s * SEQ + row];
  f32x4 acc;
#pragma unroll
  for (int e = 0; e < 4; ++e) acc[e] = 0.f;
  for (int s = 0; s < ksplit; ++s) {
    f32x4 o = *(const f32x4*)&Opart[((size_t)s * SEQ + row) * HD + c0];
#pragma unroll
    for (int e = 0; e < 4; ++e) acc[e] += o[e];
  }
  const float inv = 1.0f / lsum;
  f32x4 res;
#pragma unroll
  for (int e = 0; e < 4; ++e) res[e] = acc[e] * inv;
  *(f32x4*)&out[(size_t)row * HD + c0] = res;
}

extern "C" void kernel_launch(void* const* d_in, const int* in_sizes, int n_in,
                              void* d_out, int out_size, void* d_ws, size_t ws_size,
                              hipStream_t stream) {
  const float* Q = (const float*)d_in[0];
  const float* K = (const float*)d_in[1];
  const float* V = (const float*)d_in[2];
  float* out = (float*)d_out;

  int ksplit = 8, kshift = 3;
  while (ksplit > 1) {
    size_t need = (size_t)ksplit * SEQ * HD * 4
                + (size_t)ksplit * SEQ * 4
                + (size_t)SEQ * HD * 2 * 2;
    if (need <= ws_size) break;
    ksplit >>= 1; kshift--;
  }

  char* ws = (char*)d_ws;
  float* Opart = (float*)ws;
  float* Lpart = (float*)(ws + (size_t)ksplit * SEQ * HD * 4);
  bf16_t* Kb = (bf16_t*)(ws + (size_t)ksplit * SEQ * HD * 4 + (size_t)ksplit * SEQ * 4);
  bf16_t* VT = Kb + (size_t)SEQ * HD;

  const int nit = SEQ / (ksplit * BN);

  prep_kernel<<<768, 256, 0, stream>>>(K, V, Kb, VT);
  fattn_kernel<<<NQT * ksplit, THREADS, 0, stream>>>(Q, Kb, VT, Opart, Lpart, kshift, nit);
  combine_kernel<<<SEQ / 8, 256, 0, stream>>>(Opart, Lpart, out, ksplit);
}